// Round 7
// baseline (36.405 us; speedup 1.0000x reference)
//
#include <hip/hip_runtime.h>

#define TT 256
#define HH 512
#define WW 512
#define LOG2E 1.44269504088896340736f
#define KS (100.0f * LOG2E)
#define STEP (1.0f / 511.0f)
#define RUN 4      // consecutive y-pixels per thread (2 A/B pairs)
#define CHUNK 32   // triangles per wave (8 waves cover all 256)

// ws layout (floats):
//  [0 .. 16*TT)   : per-triangle 16-float record
//    {Dy0,Dx0,C0, Dy1,Dx1,C1, Dy2,Dx2,C2, k0,k1,k2, expd, expd*cr, expd*cg, expd*cb}
//    E_i(x,y) = x*Dy_i - y*Dx_i + C_i (pre-scaled by SHARPNESS*log2e)
//    u_i = 2^-E_i ; y -> y+STEP multiplies u_i by k_i = 2^(STEP*Dx_i)
//  [16*TT .. +4)  : eps baseline (S, Sr, Sg, Sb)
__global__ __launch_bounds__(256) void tri_setup(
        const float* __restrict__ verts,
        const float* __restrict__ colors,
        const float* __restrict__ depth,
        float* __restrict__ ws) {
    int t = threadIdx.x;

    float v0x = verts[t * 6 + 0], v0y = verts[t * 6 + 1];
    float v1x = verts[t * 6 + 2], v1y = verts[t * 6 + 3];
    float v2x = verts[t * 6 + 4], v2y = verts[t * 6 + 5];

    float dx0 = v1x - v0x, dy0 = v1y - v0y;
    float dx1 = v2x - v1x, dy1 = v2y - v1y;
    float dx2 = v0x - v2x, dy2 = v0y - v2y;
    float c0 = v0y * dx0 - v0x * dy0;
    float c1 = v1y * dx1 - v1x * dy1;
    float c2 = v2y * dx2 - v2x * dy2;

    float expd = __builtin_amdgcn_exp2f(depth[t] * LOG2E);
    float cr = colors[t * 3 + 0], cg = colors[t * 3 + 1], cb = colors[t * 3 + 2];
    float ecr = expd * cr, ecg = expd * cg, ecb = expd * cb;

    float* f = ws + t * 16;
    f[0] = KS * dy0;  f[1] = KS * dx0;  f[2] = KS * c0;
    f[3] = KS * dy1;  f[4] = KS * dx1;  f[5] = KS * c1;
    f[6] = KS * dy2;  f[7] = KS * dx2;  f[8] = KS * c2;
    f[9]  = __builtin_amdgcn_exp2f(STEP * (KS * dx0));
    f[10] = __builtin_amdgcn_exp2f(STEP * (KS * dx1));
    f[11] = __builtin_amdgcn_exp2f(STEP * (KS * dx2));
    f[12] = expd; f[13] = ecr; f[14] = ecg; f[15] = ecb;

    // deterministic single-pass float4 tree reduction of the eps baseline
    __shared__ float4 red[256];
    red[t] = make_float4(expd * 1e-6f, ecr * 1e-6f, ecg * 1e-6f, ecb * 1e-6f);
    __syncthreads();
    for (int s = 128; s > 0; s >>= 1) {
        if (t < s) {
            float4 a = red[t], b = red[t + s];
            red[t] = make_float4(a.x + b.x, a.y + b.y, a.z + b.z, a.w + b.w);
        }
        __syncthreads();
    }
    if (t == 0) {
        ws[16 * TT + 0] = red[0].x;
        ws[16 * TT + 1] = red[0].y;
        ws[16 * TT + 2] = red[0].z;
        ws[16 * TT + 3] = red[0].w;
    }
}

__global__ __launch_bounds__(512, 8) void tri_render(
        const float* __restrict__ ws,
        float* __restrict__ out) {
    __shared__ float4 s_part[4][RUN][64];   // 16 KiB

    int tid  = threadIdx.x;
    int lane = tid & 63;
    int wave = __builtin_amdgcn_readfirstlane(tid >> 6);   // 0..7

    int bx = blockIdx.x & 7;    // 8 x-strips of 64
    int by = blockIdx.x >> 3;   // 128 y-runs of 4

    float px  = (float)(bx * 64 + lane) * STEP;
    float py0 = (float)(by * RUN) * STEP;

    float acc[RUN][4];
    #pragma unroll
    for (int i = 0; i < RUN; ++i) {
        acc[i][0] = 0.0f; acc[i][1] = 0.0f; acc[i][2] = 0.0f; acc[i][3] = 0.0f;
    }

    const float* tbase = ws + wave * (CHUNK * 16);

    #pragma unroll 2
    for (int j = 0; j < CHUNK; ++j) {
        const float* tp = tbase + (j << 4);
        float Dy0 = tp[0],  Dx0 = tp[1],  C0 = tp[2];
        float Dy1 = tp[3],  Dx1 = tp[4],  C1 = tp[5];
        float Dy2 = tp[6],  Dx2 = tp[7],  C2 = tp[8];

        // u_i = 2^(n_i) at (px, py0); n = -E = py*Dx - px*Dy - C
        float n0 = fmaf(py0, Dx0, -C0);  n0 = fmaf(-px, Dy0, n0);
        float n1 = fmaf(py0, Dx1, -C1);  n1 = fmaf(-px, Dy1, n1);
        float n2 = fmaf(py0, Dx2, -C2);  n2 = fmaf(-px, Dy2, n2);

        // Far-outside skip: |dn/row| <= 3*STEP*|Dx| < 0.5 over the 4-row run,
        // so nmax>34 everywhere => mask < ~2^-32 for the whole run -> drop.
        float nmax = fmaxf(fmaxf(n0, n1), n2);
        if (__all(nmax > 34.0f)) continue;

        float u0 = __builtin_amdgcn_exp2f(n0);
        float u1 = __builtin_amdgcn_exp2f(n1);
        float u2 = __builtin_amdgcn_exp2f(n2);
        float k0 = tp[9], k1 = tp[10], k2 = tp[11];          // wave-uniform (SGPR)
        float ce = tp[12], cr = tp[13], cg = tp[14], cb = tp[15];

        #pragma unroll
        for (int i = 0; i < RUN / 2; ++i) {
            // pixel A at y-row 2i
            float a  = u1 + 1.0f;
            float PA = fmaf(u0, a, a);      // (1+u0)(1+u1)
            PA = fmaf(u2, PA, PA);          // *(1+u2)
            PA = fminf(PA, 1e18f);          // overflow/NaN guard (min picks 1e18)
            u0 *= k0; u1 *= k1; u2 *= k2;   // advance one row
            // pixel B at y-row 2i+1
            a = u1 + 1.0f;
            float PB = fmaf(u0, a, a);
            PB = fmaf(u2, PB, PB);
            PB = fminf(PB, 1e18f);
            if (i != RUN / 2 - 1) { u0 *= k0; u1 *= k1; u2 *= k2; }

            float rinv = __builtin_amdgcn_rcpf(PA * PB);   // one rcp / 2 px
            float wA = rinv * PB;           // mask_A
            float wB = rinv * PA;           // mask_B

            acc[2*i][0]   = fmaf(wA, ce, acc[2*i][0]);
            acc[2*i+1][0] = fmaf(wB, ce, acc[2*i+1][0]);
            acc[2*i][1]   = fmaf(wA, cr, acc[2*i][1]);
            acc[2*i+1][1] = fmaf(wB, cr, acc[2*i+1][1]);
            acc[2*i][2]   = fmaf(wA, cg, acc[2*i][2]);
            acc[2*i+1][2] = fmaf(wB, cg, acc[2*i+1][2]);
            acc[2*i][3]   = fmaf(wA, cb, acc[2*i][3]);
            acc[2*i+1][3] = fmaf(wB, cb, acc[2*i+1][3]);
        }
    }

    // two-stage deterministic reduction across the 8 waves
    if (wave >= 4) {
        #pragma unroll
        for (int i = 0; i < RUN; ++i)
            s_part[wave - 4][i][lane] =
                make_float4(acc[i][0], acc[i][1], acc[i][2], acc[i][3]);
    }
    __syncthreads();
    if (wave < 4) {
        #pragma unroll
        for (int i = 0; i < RUN; ++i) {
            float4 v = s_part[wave][i][lane];
            v.x += acc[i][0]; v.y += acc[i][1];
            v.z += acc[i][2]; v.w += acc[i][3];
            s_part[wave][i][lane] = v;
        }
    }
    __syncthreads();

    // finalize: first 256 threads -> 256 pixels (64 x 4 tile)
    if (tid < 64 * RUN) {
        const float* base = ws + 16 * TT;
        float b0 = base[0], b1 = base[1], b2 = base[2], b3 = base[3];

        int i = tid >> 6, l = tid & 63;
        float4 v0 = s_part[0][i][l];
        float4 v1 = s_part[1][i][l];
        float4 v2 = s_part[2][i][l];
        float4 v3 = s_part[3][i][l];
        float sum = b0 + ((v0.x + v1.x) + (v2.x + v3.x));
        float r   = b1 + ((v0.y + v1.y) + (v2.y + v3.y));
        float g   = b2 + ((v0.z + v1.z) + (v2.z + v3.z));
        float bch = b3 + ((v0.w + v1.w) + (v2.w + v3.w));
        float inv = 1.0f / sum;
        int gy = by * RUN + i;
        int gx = bx * 64 + l;
        int pix = gy * WW + gx;
        out[pix]               = r   * inv;
        out[HH * WW + pix]     = g   * inv;
        out[2 * HH * WW + pix] = bch * inv;
    }
}

extern "C" void kernel_launch(void* const* d_in, const int* in_sizes, int n_in,
                              void* d_out, int out_size, void* d_ws, size_t ws_size,
                              hipStream_t stream) {
    const float* verts  = (const float*)d_in[0];
    const float* colors = (const float*)d_in[1];
    const float* depth  = (const float*)d_in[2];
    float* out = (float*)d_out;
    float* ws  = (float*)d_ws;   // 16 KiB + 16 B

    tri_setup<<<dim3(1), dim3(256), 0, stream>>>(verts, colors, depth, ws);
    tri_render<<<dim3((WW / 64) * (HH / RUN)), dim3(512), 0, stream>>>(ws, out);
}

// Round 8
// 31.444 us; speedup vs baseline: 1.1578x; 1.1578x over previous
//
#include <hip/hip_runtime.h>

#define TT 256
#define HH 512
#define WW 512
#define LOG2E 1.44269504088896340736f
#define KS (100.0f * LOG2E)
#define STEP (1.0f / 511.0f)
#define RUN 4      // consecutive y-pixels per thread (2 A/B pairs)
#define CHUNK 32   // triangles per wave (8 waves cover all 256)

// Single fused kernel. Per block:
//  phase 1: threads 0..255 build triangle records into LDS
//    rec[t] = 4 x float4: {Dy0,Dx0,C0,Dy1},{Dx1,C1,Dy2,Dx2},{C2,k0,k1,k2},
//             {expd, expd*cr, expd*cg, expd*cb}
//    eps[t] = (se, se*cr, se*cg, se*cb), se = expd*1e-6
//  phase 2: every wave reduces eps[] to the baseline via shuffles (no sync)
//  phase 3: each wave accumulates its 32 triangles over the 64x4 tile
//  phase 4: two-stage LDS reduction across 8 waves, finalize 256 pixels
__global__ __launch_bounds__(512, 8) void tri_render(
        const float* __restrict__ verts,
        const float* __restrict__ colors,
        const float* __restrict__ depth,
        float* __restrict__ out) {
    __shared__ float4 s_rec[TT][4];          // 16 KiB
    __shared__ float4 s_eps[TT];             // 4 KiB
    __shared__ float4 s_part[4][RUN][64];    // 16 KiB   (36 KiB total)

    int tid  = threadIdx.x;
    int lane = tid & 63;
    int wave = __builtin_amdgcn_readfirstlane(tid >> 6);   // 0..7

    // ---------- phase 1: build records ----------
    if (tid < TT) {
        int t = tid;
        float v0x = verts[t * 6 + 0], v0y = verts[t * 6 + 1];
        float v1x = verts[t * 6 + 2], v1y = verts[t * 6 + 3];
        float v2x = verts[t * 6 + 4], v2y = verts[t * 6 + 5];

        // edge(p,va,vb) = px*dy - py*dx + (ay*dx - ax*dy), scaled by KS
        float dx0 = v1x - v0x, dy0 = v1y - v0y;
        float dx1 = v2x - v1x, dy1 = v2y - v1y;
        float dx2 = v0x - v2x, dy2 = v0y - v2y;
        float c0 = v0y * dx0 - v0x * dy0;
        float c1 = v1y * dx1 - v1x * dy1;
        float c2 = v2y * dx2 - v2x * dy2;

        float expd = __builtin_amdgcn_exp2f(depth[t] * LOG2E);
        float cr = colors[t * 3 + 0], cg = colors[t * 3 + 1], cb = colors[t * 3 + 2];

        s_rec[t][0] = make_float4(KS * dy0, KS * dx0, KS * c0, KS * dy1);
        s_rec[t][1] = make_float4(KS * dx1, KS * c1, KS * dy2, KS * dx2);
        s_rec[t][2] = make_float4(KS * c2,
                                  __builtin_amdgcn_exp2f(STEP * (KS * dx0)),
                                  __builtin_amdgcn_exp2f(STEP * (KS * dx1)),
                                  __builtin_amdgcn_exp2f(STEP * (KS * dx2)));
        s_rec[t][3] = make_float4(expd, expd * cr, expd * cg, expd * cb);
        float se = expd * 1e-6f;
        s_eps[t] = make_float4(se, se * cr, se * cg, se * cb);
    }
    __syncthreads();

    // ---------- phase 2: per-wave baseline reduction (deterministic) ----------
    float4 e0 = s_eps[lane];
    float4 e1 = s_eps[lane + 64];
    float4 e2 = s_eps[lane + 128];
    float4 e3 = s_eps[lane + 192];
    float b0 = (e0.x + e1.x) + (e2.x + e3.x);
    float b1 = (e0.y + e1.y) + (e2.y + e3.y);
    float b2 = (e0.z + e1.z) + (e2.z + e3.z);
    float b3 = (e0.w + e1.w) + (e2.w + e3.w);
    #pragma unroll
    for (int d = 1; d < 64; d <<= 1) {
        b0 += __shfl_xor(b0, d, 64);
        b1 += __shfl_xor(b1, d, 64);
        b2 += __shfl_xor(b2, d, 64);
        b3 += __shfl_xor(b3, d, 64);
    }

    // ---------- phase 3: main accumulation ----------
    int bx = blockIdx.x & 7;    // 8 x-strips of 64
    int by = blockIdx.x >> 3;   // 128 y-runs of 4

    float px  = (float)(bx * 64 + lane) * STEP;
    float py0 = (float)(by * RUN) * STEP;

    float acc[RUN][4];
    #pragma unroll
    for (int i = 0; i < RUN; ++i) {
        acc[i][0] = 0.0f; acc[i][1] = 0.0f; acc[i][2] = 0.0f; acc[i][3] = 0.0f;
    }

    const float4* rec = &s_rec[wave * CHUNK][0];

    #pragma unroll 1
    for (int j = 0; j < CHUNK; ++j) {
        float4 q0 = rec[j * 4 + 0];
        float4 q1 = rec[j * 4 + 1];
        float4 q2 = rec[j * 4 + 2];
        float4 q3 = rec[j * 4 + 3];

        // u_i = 2^(n_i) at (px, py0); n = -E = py*Dx - px*Dy - C
        float n0 = fmaf(py0, q0.y, -q0.z);  n0 = fmaf(-px, q0.x, n0);
        float n1 = fmaf(py0, q1.x, -q1.y);  n1 = fmaf(-px, q0.w, n1);
        float n2 = fmaf(py0, q1.w, -q2.x);  n2 = fmaf(-px, q1.z, n2);
        float u0 = __builtin_amdgcn_exp2f(n0);
        float u1 = __builtin_amdgcn_exp2f(n1);
        float u2 = __builtin_amdgcn_exp2f(n2);
        float k0 = q2.y, k1 = q2.z, k2 = q2.w;
        float ce = q3.x, cr = q3.y, cg = q3.z, cb = q3.w;

        #pragma unroll
        for (int i = 0; i < RUN / 2; ++i) {
            // pixel A at y-row 2i
            float a  = u1 + 1.0f;
            float PA = fmaf(u0, a, a);      // (1+u0)(1+u1)
            PA = fmaf(u2, PA, PA);          // *(1+u2)
            PA = fminf(PA, 1e18f);          // overflow/NaN guard
            u0 *= k0; u1 *= k1; u2 *= k2;   // advance one row
            // pixel B at y-row 2i+1
            a = u1 + 1.0f;
            float PB = fmaf(u0, a, a);
            PB = fmaf(u2, PB, PB);
            PB = fminf(PB, 1e18f);
            if (i != RUN / 2 - 1) { u0 *= k0; u1 *= k1; u2 *= k2; }

            float rinv = __builtin_amdgcn_rcpf(PA * PB);   // one rcp / 2 px
            float wA = rinv * PB;           // mask_A
            float wB = rinv * PA;           // mask_B

            acc[2*i][0]   = fmaf(wA, ce, acc[2*i][0]);
            acc[2*i+1][0] = fmaf(wB, ce, acc[2*i+1][0]);
            acc[2*i][1]   = fmaf(wA, cr, acc[2*i][1]);
            acc[2*i+1][1] = fmaf(wB, cr, acc[2*i+1][1]);
            acc[2*i][2]   = fmaf(wA, cg, acc[2*i][2]);
            acc[2*i+1][2] = fmaf(wB, cg, acc[2*i+1][2]);
            acc[2*i][3]   = fmaf(wA, cb, acc[2*i][3]);
            acc[2*i+1][3] = fmaf(wB, cb, acc[2*i+1][3]);
        }
    }
    __syncthreads();   // phase-1 LDS (s_rec) no longer needed beyond here? it is — only s_part reused below; s_eps/s_rec untouched. Barrier orders acc write-out.

    // ---------- phase 4: two-stage reduction across the 8 waves ----------
    if (wave >= 4) {
        #pragma unroll
        for (int i = 0; i < RUN; ++i)
            s_part[wave - 4][i][lane] =
                make_float4(acc[i][0], acc[i][1], acc[i][2], acc[i][3]);
    }
    __syncthreads();
    if (wave < 4) {
        #pragma unroll
        for (int i = 0; i < RUN; ++i) {
            float4 v = s_part[wave][i][lane];
            v.x += acc[i][0]; v.y += acc[i][1];
            v.z += acc[i][2]; v.w += acc[i][3];
            s_part[wave][i][lane] = v;
        }
    }
    __syncthreads();

    // finalize: first 256 threads -> 256 pixels (64 x 4 tile)
    if (tid < 64 * RUN) {
        int i = tid >> 6, l = tid & 63;
        float4 v0 = s_part[0][i][l];
        float4 v1 = s_part[1][i][l];
        float4 v2 = s_part[2][i][l];
        float4 v3 = s_part[3][i][l];
        float sum = b0 + ((v0.x + v1.x) + (v2.x + v3.x));
        float r   = b1 + ((v0.y + v1.y) + (v2.y + v3.y));
        float g   = b2 + ((v0.z + v1.z) + (v2.z + v3.z));
        float bch = b3 + ((v0.w + v1.w) + (v2.w + v3.w));
        float inv = 1.0f / sum;
        int gy = by * RUN + i;
        int gx = bx * 64 + l;
        int pix = gy * WW + gx;
        out[pix]               = r   * inv;
        out[HH * WW + pix]     = g   * inv;
        out[2 * HH * WW + pix] = bch * inv;
    }
}

extern "C" void kernel_launch(void* const* d_in, const int* in_sizes, int n_in,
                              void* d_out, int out_size, void* d_ws, size_t ws_size,
                              hipStream_t stream) {
    const float* verts  = (const float*)d_in[0];
    const float* colors = (const float*)d_in[1];
    const float* depth  = (const float*)d_in[2];
    float* out = (float*)d_out;

    tri_render<<<dim3((WW / 64) * (HH / RUN)), dim3(512), 0, stream>>>(
        verts, colors, depth, out);
}